// Round 1
// 716.652 us; speedup vs baseline: 1.9509x; 1.9509x over previous
//
#include <hip/hip_runtime.h>
#include <hip/hip_bf16.h>
#include <math.h>

typedef unsigned short u16;
typedef unsigned int u32;

#define B 16
#define NH 32
#define NKV 8
#define DK 128
#define DM 4096
#define MAXBLK 256
#define CS 512          // attention chunk size (tokens)
#define NCHUNK 8        // 4096 / CS

// ---- ws layout (float offsets) ---- (unchanged from previous version)
#define WS_FLAG   0          // [16] int flag at [0]
#define WS_QKV    16         // [6144][16]              98304
#define WS_QROPE  98320      // [B][NH][DK]             65536
#define WS_KVNEW  163856     // [B][2][NKV][DK]         32768
#define WS_PARTML 196624     // [B][NH][NCHUNK][2]       8192
#define WS_PARTAC 204816     // [B][NH][NCHUNK][DK]    524288
#define WS_ATTN   729104     // [B][NH*DK] fp32         65536
#define WS_TOTAL  794640     // floats = 3.03 MB

__device__ __forceinline__ float bfu(u16 h) { return __uint_as_float(((u32)h) << 16); }
__device__ __forceinline__ float bl(u32 u) { return __uint_as_float(u << 16); }
__device__ __forceinline__ float bh(u32 u) { return __uint_as_float(u & 0xffff0000u); }
__device__ __forceinline__ u16 f2bf(float f) {
    u32 u = __float_as_uint(f);
    u += 0x7fffu + ((u >> 16) & 1);   // RNE
    return (u16)(u >> 16);
}

// ------- kernel 0: detect dtype of float tensors (0 = bf16, 1 = fp32) -------
__global__ void detect_dtype(const void* __restrict__ x, int* __restrict__ flag) {
    int lane = threadIdx.x;   // 64
    int sane = 0;
#pragma unroll
    for (int j = 0; j < 2; ++j) {
        u16 h = ((const u16*)x)[lane * 2 + j];
        float v = bfu(h);
        float a = fabsf(v);
        if (v == 0.0f || (a >= 9e-4f && a <= 64.0f)) sane++;
    }
#pragma unroll
    for (int off = 32; off > 0; off >>= 1) sane += __shfl_xor(sane, off);
    if (lane == 0) flag[0] = (sane >= 100) ? 0 : 1;
}

// =====================================================================
// GEMV kernels: block = 8 rows (2 per wave), X[16][1024-slice] in LDS.
// W elements read exactly once; 16 batch-accumulators per lane.
// =====================================================================
#define XS_SLICE 1024

// ------- kernel 1: QKV projection -------
__global__ __launch_bounds__(256) void qkv_gemv(
    const void* __restrict__ x, const void* __restrict__ wq,
    const void* __restrict__ wk, const void* __restrict__ wv,
    const int* __restrict__ flag, float* __restrict__ qkv /* [6144][16] */) {
    __shared__ float xs[16 * XS_SLICE];   // 64 KB
    int isf32 = flag[0];
    int tid = threadIdx.x;
    int wid = tid >> 6, lane = tid & 63;
    int r0 = blockIdx.x * 8 + wid * 2;
    int r1 = r0 + 1;

    const void* wb0; size_t ro0;
    if (r0 < 4096)      { wb0 = wq; ro0 = (size_t)r0 * DM; }
    else if (r0 < 5120) { wb0 = wk; ro0 = (size_t)(r0 - 4096) * DM; }
    else                { wb0 = wv; ro0 = (size_t)(r0 - 5120) * DM; }
    const void* wb1; size_t ro1;
    if (r1 < 4096)      { wb1 = wq; ro1 = (size_t)r1 * DM; }
    else if (r1 < 5120) { wb1 = wk; ro1 = (size_t)(r1 - 4096) * DM; }
    else                { wb1 = wv; ro1 = (size_t)(r1 - 5120) * DM; }

    float acc0[16], acc1[16];
#pragma unroll
    for (int i = 0; i < 16; ++i) { acc0[i] = 0.f; acc1[i] = 0.f; }

    for (int s = 0; s < 4; ++s) {
        if (s) __syncthreads();
        int off = s * XS_SLICE;
        // ---- stage X slice to LDS (fp32) ----
        if (isf32) {
#pragma unroll
            for (int i = 0; i < 16; ++i) {
                int flat = (i * 256 + tid) * 4;
                int bb = flat >> 10, c = flat & 1023;
                *(float4*)(xs + bb * XS_SLICE + c) =
                    *(const float4*)((const float*)x + (size_t)bb * DM + off + c);
            }
        } else {
#pragma unroll
            for (int i = 0; i < 8; ++i) {
                int flat = (i * 256 + tid) * 8;
                int bb = flat >> 10, c = flat & 1023;
                uint4 u = *(const uint4*)((const u16*)x + (size_t)bb * DM + off + c);
                float* d = xs + bb * XS_SLICE + c;
                d[0] = bl(u.x); d[1] = bh(u.x); d[2] = bl(u.y); d[3] = bh(u.y);
                d[4] = bl(u.z); d[5] = bh(u.z); d[6] = bl(u.w); d[7] = bh(u.w);
            }
        }
        __syncthreads();

        // ---- compute: stream W, FMA against LDS X ----
        if (isf32) {
            const float* W0 = (const float*)wb0 + ro0 + off;
            const float* W1 = (const float*)wb1 + ro1 + off;
            float4 wr0[4], wr1[4];
#pragma unroll
            for (int it = 0; it < 4; ++it) wr0[it] = *(const float4*)(W0 + it * 256 + lane * 4);
#pragma unroll
            for (int it = 0; it < 4; ++it) wr1[it] = *(const float4*)(W1 + it * 256 + lane * 4);
#pragma unroll
            for (int it = 0; it < 4; ++it) {
                int j = it * 256 + lane * 4;
#pragma unroll
                for (int bb = 0; bb < 16; ++bb) {
                    float4 x4 = *(const float4*)(xs + bb * XS_SLICE + j);
                    acc0[bb] += wr0[it].x * x4.x + wr0[it].y * x4.y + wr0[it].z * x4.z + wr0[it].w * x4.w;
                    acc1[bb] += wr1[it].x * x4.x + wr1[it].y * x4.y + wr1[it].z * x4.z + wr1[it].w * x4.w;
                }
            }
        } else {
            const u16* W0 = (const u16*)wb0 + ro0 + off;
            const u16* W1 = (const u16*)wb1 + ro1 + off;
            uint4 u0[2], u1[2];
#pragma unroll
            for (int it = 0; it < 2; ++it) u0[it] = *(const uint4*)(W0 + it * 512 + lane * 8);
#pragma unroll
            for (int it = 0; it < 2; ++it) u1[it] = *(const uint4*)(W1 + it * 512 + lane * 8);
#pragma unroll
            for (int it = 0; it < 2; ++it) {
                int j = it * 512 + lane * 8;
                float w00 = bl(u0[it].x), w01 = bh(u0[it].x), w02 = bl(u0[it].y), w03 = bh(u0[it].y);
                float w04 = bl(u0[it].z), w05 = bh(u0[it].z), w06 = bl(u0[it].w), w07 = bh(u0[it].w);
                float w10 = bl(u1[it].x), w11 = bh(u1[it].x), w12 = bl(u1[it].y), w13 = bh(u1[it].y);
                float w14 = bl(u1[it].z), w15 = bh(u1[it].z), w16 = bl(u1[it].w), w17 = bh(u1[it].w);
#pragma unroll
                for (int bb = 0; bb < 16; ++bb) {
                    const float* xp = xs + bb * XS_SLICE + j;
                    float4 xa = *(const float4*)(xp);
                    float4 xb = *(const float4*)(xp + 4);
                    acc0[bb] += w00 * xa.x + w01 * xa.y + w02 * xa.z + w03 * xa.w
                              + w04 * xb.x + w05 * xb.y + w06 * xb.z + w07 * xb.w;
                    acc1[bb] += w10 * xa.x + w11 * xa.y + w12 * xa.z + w13 * xa.w
                              + w14 * xb.x + w15 * xb.y + w16 * xb.z + w17 * xb.w;
                }
            }
        }
    }

    // ---- cross-lane reduce: 16 batch sums per row ----
    float out0 = 0.f, out1 = 0.f;
#pragma unroll
    for (int bb = 0; bb < 16; ++bb) {
        float v0 = acc0[bb], v1 = acc1[bb];
#pragma unroll
        for (int o = 32; o > 0; o >>= 1) { v0 += __shfl_xor(v0, o); v1 += __shfl_xor(v1, o); }
        if (lane == bb) { out0 = v0; out1 = v1; }
    }
    if (lane < 16) {
        qkv[(size_t)r0 * 16 + lane] = out0;
        qkv[(size_t)r1 * 16 + lane] = out1;
    }
}

// ------- kernel 2: RoPE + pack q/k/v (all fp32 in ws) -------
__global__ __launch_bounds__(256) void rope_pack(
    const float* __restrict__ qkv, const int* __restrict__ positions,
    float* __restrict__ q_rope /* [B][NH][DK] */,
    float* __restrict__ kv_new /* [B][2][NKV][DK] */) {
    int tid = blockIdx.x * 256 + threadIdx.x;   // 0..98303
    int r = tid >> 4, b = tid & 15;
    float s = qkv[(size_t)r * 16 + b];
    if (r < 5120) {
        int base = (r < 4096) ? 0 : 4096;
        int loc = r - base;
        int head = loc >> 7, d = loc & 127;
        int j = d & 63;
        int rp = base + head * 128 + ((d < 64) ? d + 64 : d - 64);
        float sp = qkv[(size_t)rp * 16 + b];
        float pos = (float)positions[b];
        float inv_freq = __expf(-(float)j * (9.210340371976184f / 64.0f));
        float ang = pos * inv_freq;
        float cv = cosf(ang), sv = sinf(ang);
        float out = (d < 64) ? (s * cv - sp * sv) : (s * cv + sp * sv);
        if (r < 4096) q_rope[((size_t)b * NH + head) * DK + d] = out;
        else          kv_new[(((size_t)b * 2 + 0) * NKV + head) * DK + d] = out;
    } else {
        int loc = r - 5120;
        int kvh = loc >> 7, d = loc & 127;
        kv_new[(((size_t)b * 2 + 1) * NKV + kvh) * DK + d] = s;
    }
}

// =====================================================================
// kernel 3: flash-decode partials, restructured:
//  - 512 threads (8 waves); wave w owns token slice [w*64, w*64+64)
//  - each wave computes ALL 4 heads of its kv group -> K,V read 1x per block
//  - phase A: 8 lanes per token (128 B contiguous per token per load inst)
//  - softmax via LDS (waves 0..3, one head each)
//  - phase B: per-wave PV partials for 4 heads, LDS cross-wave reduce
// =====================================================================
__device__ __forceinline__ void dot16_f32(
    const float* __restrict__ kr,
    const float* __restrict__ q0, const float* __restrict__ q1,
    const float* __restrict__ q2, const float* __restrict__ q3,
    float& a0, float& a1, float& a2, float& a3) {
#pragma unroll
    for (int c = 0; c < 4; ++c) {
        float4 k4 = *(const float4*)(kr + c * 4);
        float4 q4;
        q4 = *(const float4*)(q0 + c * 4);
        a0 += k4.x * q4.x + k4.y * q4.y + k4.z * q4.z + k4.w * q4.w;
        q4 = *(const float4*)(q1 + c * 4);
        a1 += k4.x * q4.x + k4.y * q4.y + k4.z * q4.z + k4.w * q4.w;
        q4 = *(const float4*)(q2 + c * 4);
        a2 += k4.x * q4.x + k4.y * q4.y + k4.z * q4.z + k4.w * q4.w;
        q4 = *(const float4*)(q3 + c * 4);
        a3 += k4.x * q4.x + k4.y * q4.y + k4.z * q4.z + k4.w * q4.w;
    }
}

__device__ __forceinline__ void dot16_bf16(
    const u16* __restrict__ kr,
    const float* __restrict__ q0, const float* __restrict__ q1,
    const float* __restrict__ q2, const float* __restrict__ q3,
    float& a0, float& a1, float& a2, float& a3) {
#pragma unroll
    for (int u = 0; u < 2; ++u) {
        uint4 uu = *(const uint4*)(kr + u * 8);
        float k0 = bl(uu.x), k1 = bh(uu.x), k2 = bl(uu.y), k3 = bh(uu.y);
        float k4 = bl(uu.z), k5 = bh(uu.z), k6 = bl(uu.w), k7 = bh(uu.w);
        int dd = u * 8;
        float4 qa, qb;
        qa = *(const float4*)(q0 + dd); qb = *(const float4*)(q0 + dd + 4);
        a0 += k0 * qa.x + k1 * qa.y + k2 * qa.z + k3 * qa.w
            + k4 * qb.x + k5 * qb.y + k6 * qb.z + k7 * qb.w;
        qa = *(const float4*)(q1 + dd); qb = *(const float4*)(q1 + dd + 4);
        a1 += k0 * qa.x + k1 * qa.y + k2 * qa.z + k3 * qa.w
            + k4 * qb.x + k5 * qb.y + k6 * qb.z + k7 * qb.w;
        qa = *(const float4*)(q2 + dd); qb = *(const float4*)(q2 + dd + 4);
        a2 += k0 * qa.x + k1 * qa.y + k2 * qa.z + k3 * qa.w
            + k4 * qb.x + k5 * qb.y + k6 * qb.z + k7 * qb.w;
        qa = *(const float4*)(q3 + dd); qb = *(const float4*)(q3 + dd + 4);
        a3 += k0 * qa.x + k1 * qa.y + k2 * qa.z + k3 * qa.w
            + k4 * qb.x + k5 * qb.y + k6 * qb.z + k7 * qb.w;
    }
}

__global__ __launch_bounds__(512) void attn_partial(
    const void* __restrict__ kpool, const void* __restrict__ vpool,
    const int* __restrict__ positions, const int* __restrict__ btab,
    const float* __restrict__ q_rope, const float* __restrict__ kv_new,
    const int* __restrict__ flag,
    float* __restrict__ part_ml /* [B][NH][NCHUNK][2] */,
    float* __restrict__ part_acc /* [B][NH][NCHUNK][DK] */) {
    int chunk = blockIdx.x, kv = blockIdx.y, b = blockIdx.z;
    int pos = positions[b], len = pos + 1;
    int cs = chunk * CS;
    if (cs >= len) return;
    int count = min(CS, len - cs);
    int isf32 = flag[0];

    __shared__ float q_s[4 * DK];          //  2 KB
    __shared__ float s_s[4][CS];           //  8 KB (scores, then p)
    __shared__ float red_s[8][4][DK];      // 16 KB

    int tid = threadIdx.x;
    int w = tid >> 6, lane = tid & 63;

    q_s[tid] = q_rope[((size_t)b * NH + kv * 4) * DK + tid];
    __syncthreads();

    int tgroup = lane >> 3, lig = lane & 7;
    int d0 = lig * 16;
    const float* q0 = q_s + d0;
    const float* q1 = q_s + DK + d0;
    const float* q2 = q_s + 2 * DK + d0;
    const float* q3 = q_s + 3 * DK + d0;
    const int* bt = btab + b * MAXBLK;
    const float scale = 0.08838834764831845f;   // 1/sqrt(128)
    int tbase = w * 64;
    const float* knew = kv_new + (((size_t)b * 2 + 0) * NKV + kv) * DK;
    const float* vnew = kv_new + (((size_t)b * 2 + 1) * NKV + kv) * DK;

    // ---- phase A: scores for all 4 heads, 8 tokens/pass/wave ----
    for (int pass = 0; pass < 8; ++pass) {
        int tl = tbase + pass * 8 + tgroup;
        float a0 = 0.f, a1 = 0.f, a2 = 0.f, a3 = 0.f;
        if (tl < count) {
            int t = cs + tl;
            if (t == pos) {
                dot16_f32(knew + d0, q0, q1, q2, q3, a0, a1, a2, a3);
            } else {
                int blk = bt[t >> 4];
                size_t off = ((size_t)blk * 16 + (t & 15)) * (NKV * DK) + (size_t)kv * DK + d0;
                if (isf32) dot16_f32((const float*)kpool + off, q0, q1, q2, q3, a0, a1, a2, a3);
                else       dot16_bf16((const u16*)kpool + off, q0, q1, q2, q3, a0, a1, a2, a3);
            }
        }
#pragma unroll
        for (int o = 1; o < 8; o <<= 1) {
            a0 += __shfl_xor(a0, o); a1 += __shfl_xor(a1, o);
            a2 += __shfl_xor(a2, o); a3 += __shfl_xor(a3, o);
        }
        if (lig == 0 && tl < count) {
            s_s[0][tl] = a0 * scale; s_s[1][tl] = a1 * scale;
            s_s[2][tl] = a2 * scale; s_s[3][tl] = a3 * scale;
        }
    }
    __syncthreads();

    // ---- softmax: wave w<4 handles head w ----
    if (w < 4) {
        float vv[8];
        float mx = -INFINITY;
#pragma unroll
        for (int k = 0; k < 8; ++k) {
            int t = k * 64 + lane;
            vv[k] = (t < count) ? s_s[w][t] : -INFINITY;
            mx = fmaxf(mx, vv[k]);
        }
#pragma unroll
        for (int o = 32; o > 0; o >>= 1) mx = fmaxf(mx, __shfl_xor(mx, o));
        float lsum = 0.f;
#pragma unroll
        for (int k = 0; k < 8; ++k) {
            int t = k * 64 + lane;
            float p = (t < count) ? __expf(vv[k] - mx) : 0.f;
            s_s[w][t] = p;
            lsum += p;
        }
#pragma unroll
        for (int o = 32; o > 0; o >>= 1) lsum += __shfl_xor(lsum, o);
        if (lane == 0) {
            float* ml = part_ml + (((size_t)b * NH + kv * 4 + w) * NCHUNK + chunk) * 2;
            ml[0] = mx; ml[1] = lsum;
        }
    }
    __syncthreads();

    // ---- phase B: PV partials, wave-local token slice, all 4 heads ----
    int dd = lane * 2;
    float a0x = 0.f, a0y = 0.f, a1x = 0.f, a1y = 0.f;
    float a2x = 0.f, a2y = 0.f, a3x = 0.f, a3y = 0.f;
    int cw = count - tbase; if (cw > 64) cw = 64;
    for (int i = 0; i < cw; ++i) {
        int tl = tbase + i;
        int t = cs + tl;
        float v0, v1;
        if (t == pos) {
            float2 vv2 = *(const float2*)(vnew + dd);
            v0 = vv2.x; v1 = vv2.y;
        } else {
            int blk = bt[t >> 4];
            size_t off = ((size_t)blk * 16 + (t & 15)) * (NKV * DK) + (size_t)kv * DK + dd;
            if (isf32) {
                float2 vv2 = *(const float2*)((const float*)vpool + off);
                v0 = vv2.x; v1 = vv2.y;
            } else {
                u32 u = *(const u32*)((const u16*)vpool + off);
                v0 = bl(u); v1 = bh(u);
            }
        }
        float p0 = s_s[0][tl], p1 = s_s[1][tl], p2 = s_s[2][tl], p3 = s_s[3][tl];
        a0x += p0 * v0; a0y += p0 * v1;
        a1x += p1 * v0; a1y += p1 * v1;
        a2x += p2 * v0; a2y += p2 * v1;
        a3x += p3 * v0; a3y += p3 * v1;
    }
    *(float2*)(&red_s[w][0][dd]) = make_float2(a0x, a0y);
    *(float2*)(&red_s[w][1][dd]) = make_float2(a1x, a1y);
    *(float2*)(&red_s[w][2][dd]) = make_float2(a2x, a2y);
    *(float2*)(&red_s[w][3][dd]) = make_float2(a3x, a3y);
    __syncthreads();

    // ---- cross-wave reduce: 512 threads = 4 heads x 128 dims ----
    {
        int g = tid >> 7, d = tid & 127;
        float s = 0.f;
#pragma unroll
        for (int ww = 0; ww < 8; ++ww) s += red_s[ww][g][d];
        part_acc[(((size_t)b * NH + kv * 4 + g) * NCHUNK + chunk) * DK + d] = s;
    }
}

// ------- kernel 4: combine chunks -> attn (fp32 in ws) -------
__global__ __launch_bounds__(64) void attn_combine(
    const int* __restrict__ positions, const float* __restrict__ part_ml,
    const float* __restrict__ part_acc, float* __restrict__ attn) {
    int bhid = blockIdx.x;        // b*32 + h
    int b = bhid >> 5, hh = bhid & 31;
    int lane = threadIdx.x;
    int nch = (positions[b] + CS) >> 9;   // ceil((pos+1)/CS)
    const float* ml = part_ml + (size_t)bhid * NCHUNK * 2;
    float mstar = -INFINITY;
    for (int c = 0; c < nch; ++c) mstar = fmaxf(mstar, ml[c * 2]);
    float L = 0.f;
    for (int c = 0; c < nch; ++c) L += ml[c * 2 + 1] * __expf(ml[c * 2] - mstar);
    float inv = 1.0f / L;
    int d0 = lane * 2;
    float o0 = 0.f, o1 = 0.f;
    for (int c = 0; c < nch; ++c) {
        float wc = __expf(ml[c * 2] - mstar);
        float2 a = *(const float2*)(part_acc + ((size_t)bhid * NCHUNK + c) * DK + d0);
        o0 += wc * a.x; o1 += wc * a.y;
    }
    attn[(size_t)b * (NH * DK) + hh * DK + d0]     = o0 * inv;
    attn[(size_t)b * (NH * DK) + hh * DK + d0 + 1] = o1 * inv;
}

// ------- kernel 5: output projection, LDS-staged X, 8 rows/block -------
__global__ __launch_bounds__(256) void oproj_gemv(
    const float* __restrict__ attn, const void* __restrict__ wo,
    const int* __restrict__ flag, void* __restrict__ out) {
    __shared__ float xs[16 * XS_SLICE];   // 64 KB
    int isf32 = flag[0];
    int tid = threadIdx.x;
    int wid = tid >> 6, lane = tid & 63;
    int r0 = blockIdx.x * 8 + wid * 2;
    int r1 = r0 + 1;

    float acc0[16], acc1[16];
#pragma unroll
    for (int i = 0; i < 16; ++i) { acc0[i] = 0.f; acc1[i] = 0.f; }

    for (int s = 0; s < 4; ++s) {
        if (s) __syncthreads();
        int off = s * XS_SLICE;
        // X = attn, always fp32 in ws
#pragma unroll
        for (int i = 0; i < 16; ++i) {
            int flat = (i * 256 + tid) * 4;
            int bb = flat >> 10, c = flat & 1023;
            *(float4*)(xs + bb * XS_SLICE + c) =
                *(const float4*)(attn + (size_t)bb * DM + off + c);
        }
        __syncthreads();

        if (isf32) {
            const float* W0 = (const float*)wo + (size_t)r0 * DM + off;
            const float* W1 = (const float*)wo + (size_t)r1 * DM + off;
            float4 wr0[4], wr1[4];
#pragma unroll
            for (int it = 0; it < 4; ++it) wr0[it] = *(const float4*)(W0 + it * 256 + lane * 4);
#pragma unroll
            for (int it = 0; it < 4; ++it) wr1[it] = *(const float4*)(W1 + it * 256 + lane * 4);
#pragma unroll
            for (int it = 0; it < 4; ++it) {
                int j = it * 256 + lane * 4;
#pragma unroll
                for (int bb = 0; bb < 16; ++bb) {
                    float4 x4 = *(const float4*)(xs + bb * XS_SLICE + j);
                    acc0[bb] += wr0[it].x * x4.x + wr0[it].y * x4.y + wr0[it].z * x4.z + wr0[it].w * x4.w;
                    acc1[bb] += wr1[it].x * x4.x + wr1[it].y * x4.y + wr1[it].z * x4.z + wr1[it].w * x4.w;
                }
            }
        } else {
            const u16* W0 = (const u16*)wo + (size_t)r0 * DM + off;
            const u16* W1 = (const u16*)wo + (size_t)r1 * DM + off;
            uint4 u0[2], u1[2];
#pragma unroll
            for (int it = 0; it < 2; ++it) u0[it] = *(const uint4*)(W0 + it * 512 + lane * 8);
#pragma unroll
            for (int it = 0; it < 2; ++it) u1[it] = *(const uint4*)(W1 + it * 512 + lane * 8);
#pragma unroll
            for (int it = 0; it < 2; ++it) {
                int j = it * 512 + lane * 8;
                float w00 = bl(u0[it].x), w01 = bh(u0[it].x), w02 = bl(u0[it].y), w03 = bh(u0[it].y);
                float w04 = bl(u0[it].z), w05 = bh(u0[it].z), w06 = bl(u0[it].w), w07 = bh(u0[it].w);
                float w10 = bl(u1[it].x), w11 = bh(u1[it].x), w12 = bl(u1[it].y), w13 = bh(u1[it].y);
                float w14 = bl(u1[it].z), w15 = bh(u1[it].z), w16 = bl(u1[it].w), w17 = bh(u1[it].w);
#pragma unroll
                for (int bb = 0; bb < 16; ++bb) {
                    const float* xp = xs + bb * XS_SLICE + j;
                    float4 xa = *(const float4*)(xp);
                    float4 xb = *(const float4*)(xp + 4);
                    acc0[bb] += w00 * xa.x + w01 * xa.y + w02 * xa.z + w03 * xa.w
                              + w04 * xb.x + w05 * xb.y + w06 * xb.z + w07 * xb.w;
                    acc1[bb] += w10 * xa.x + w11 * xa.y + w12 * xa.z + w13 * xa.w
                              + w14 * xb.x + w15 * xb.y + w16 * xb.z + w17 * xb.w;
                }
            }
        }
    }

    float out0 = 0.f, out1 = 0.f;
#pragma unroll
    for (int bb = 0; bb < 16; ++bb) {
        float v0 = acc0[bb], v1 = acc1[bb];
#pragma unroll
        for (int o = 32; o > 0; o >>= 1) { v0 += __shfl_xor(v0, o); v1 += __shfl_xor(v1, o); }
        if (lane == bb) { out0 = v0; out1 = v1; }
    }
    if (lane < 16) {
        if (isf32) {
            ((float*)out)[(size_t)lane * DM + r0] = out0;
            ((float*)out)[(size_t)lane * DM + r1] = out1;
        } else {
            ((u16*)out)[(size_t)lane * DM + r0] = f2bf(out0);
            ((u16*)out)[(size_t)lane * DM + r1] = f2bf(out1);
        }
    }
}

extern "C" void kernel_launch(void* const* d_in, const int* in_sizes, int n_in,
                              void* d_out, int out_size, void* d_ws, size_t ws_size,
                              hipStream_t stream) {
    if (ws_size < (size_t)WS_TOTAL * sizeof(float)) return;

    const void* x     = d_in[0];
    const void* wq    = d_in[1];
    const void* wk    = d_in[2];
    const void* wv    = d_in[3];
    const void* wo    = d_in[4];
    const void* kpool = d_in[5];
    const void* vpool = d_in[6];
    const int* positions = (const int*)d_in[7];
    const int* btab      = (const int*)d_in[8];

    float* ws = (float*)d_ws;
    int*   flag     = (int*)(ws + WS_FLAG);
    float* qkv      = ws + WS_QKV;
    float* q_rope   = ws + WS_QROPE;
    float* kv_new   = ws + WS_KVNEW;
    float* part_ml  = ws + WS_PARTML;
    float* part_acc = ws + WS_PARTAC;
    float* attn     = ws + WS_ATTN;

    hipLaunchKernelGGL(detect_dtype, dim3(1), dim3(64), 0, stream, x, flag);
    hipLaunchKernelGGL(qkv_gemv, dim3(768), dim3(256), 0, stream, x, wq, wk, wv, flag, qkv);
    hipLaunchKernelGGL(rope_pack, dim3(384), dim3(256), 0, stream, qkv, positions, q_rope, kv_new);
    hipLaunchKernelGGL(attn_partial, dim3(NCHUNK, NKV, B), dim3(512), 0, stream,
                       kpool, vpool, positions, btab, q_rope, kv_new, flag, part_ml, part_acc);
    hipLaunchKernelGGL(attn_combine, dim3(B * NH), dim3(64), 0, stream,
                       positions, part_ml, part_acc, attn);
    hipLaunchKernelGGL(oproj_gemv, dim3(512), dim3(256), 0, stream, attn, wo, flag, d_out);
}